// Round 3
// baseline (111.994 us; speedup 1.0000x reference)
//
#include <hip/hip_runtime.h>
#include <hip/hip_cooperative_groups.h>
#include <math.h>

// KANLayer: out[b,o] = sum_i C[i,o]*(sum_k basis_k(x[b,i])*W[i,o,k] + bias[i,o])
// = GEMM: out = feats[4096 x 1152] * Weff[1152 x 128] + bterm[o]
// R3: single cooperative kernel — stage A folds W*C -> BT (global, 294 KB,
//     L2-resident) + bterm, grid.sync(), stage B = basis->LDS + MFMA GEMM.
//     Removes the second dispatch + inter-kernel gap vs R2.

#define DIN   128
#define DOUT  128
#define NB    9
#define KK    (DIN * NB)    // 1152
#define BATCH 4096
#define ROWS  16            // batch rows per block
#define APAD  8             // +8 bf16 -> row stride 580 dwords (2-way LDS aliasing, free)
#define ASTR  (KK + APAD)   // 1160
#define NBLK  (BATCH / ROWS)   // 256 blocks (1 per CU -> co-resident, coop-safe)
#define NTHR  512

namespace cg = cooperative_groups;

typedef __bf16 bf16x8 __attribute__((ext_vector_type(8)));
typedef float  f32x4  __attribute__((ext_vector_type(4)));

__global__ __launch_bounds__(NTHR, 1) void kan_kernel(const float* __restrict__ x,
                                                      const float* __restrict__ W,
                                                      const float* __restrict__ bias,
                                                      const float* __restrict__ C,
                                                      __bf16* __restrict__ BT,
                                                      float* __restrict__ bterm,
                                                      float* __restrict__ out) {
    __shared__ __bf16 As[ROWS * ASTR];   // 37120 B
    const int t   = threadIdx.x;
    const int gid = blockIdx.x * NTHR + t;

    // ---- stage A: fold W*C -> BT[o][i*9+k] (bf16), and bterm[o] ----
    for (int idx = gid; idx < DOUT * KK; idx += NBLK * NTHR) {
        const int o = idx / KK;
        const int r = idx - o * KK;
        const int i = r / NB;
        const int k = r - i * NB;
        const float w = W[((size_t)i * DOUT + o) * NB + k];
        const float c = C[i * DOUT + o];
        BT[idx] = (__bf16)(w * c);
    }
    if (blockIdx.x == 0 && t < DOUT) {
        float s = 0.0f;
        #pragma unroll 8
        for (int ii = 0; ii < DIN; ++ii)
            s += bias[ii * DOUT + t] * C[ii * DOUT + t];
        bterm[t] = s;
    }

    cg::this_grid().sync();   // device-scope: BT/bterm visible to all blocks

    // ---- stage B1: basis expansion into LDS ----
    const int row0 = blockIdx.x * ROWS;
    for (int e = t; e < ROWS * DIN; e += NTHR) {
        const int r = e >> 7;            // row within tile
        const int i = e & 127;           // din index
        const float v  = x[(size_t)(row0 + r) * DIN + i];
        const float av = fabsf(v);
        float f[NB];
        f[0] = v;
        f[1] = v * v;
        f[2] = v * v * v;
        f[3] = __expf(v);
        f[4] = __logf(av + 1.0f);
        f[5] = __builtin_sqrtf(av);
        f[6] = tanhf(v);
        f[7] = __sinf(v);
        f[8] = av;
        __bf16* dst = &As[r * ASTR + i * NB];
        #pragma unroll
        for (int k = 0; k < NB; ++k) dst[k] = (__bf16)f[k];
    }
    __syncthreads();

    // ---- stage B2: MFMA GEMM ----
    // Layouts (HW-verified, guide §3): A-frag A[m=lane&15][k=quad*8+j],
    // B-frag BT[n=lane&15][k=quad*8+j], C/D col=lane&15 row=quad*4+reg.
    const int lane = t & 63;
    const int wave = t >> 6;             // 0..7 -> col tile
    const int m    = lane & 15;
    const int quad = lane >> 4;
    const int col0 = wave << 4;

    const __bf16* Ap = &As[m * ASTR + quad * 8];
    const __bf16* Bp = BT + (size_t)(col0 + m) * KK + quad * 8;

    f32x4 acc = {0.0f, 0.0f, 0.0f, 0.0f};

    #pragma unroll 6
    for (int kc = 0; kc < KK / 32; ++kc) {   // 36 iters
        bf16x8 a = *(const bf16x8*)(Ap + kc * 32);
        bf16x8 b = *(const bf16x8*)(Bp + kc * 32);
        acc = __builtin_amdgcn_mfma_f32_16x16x32_bf16(a, b, acc, 0, 0, 0);
    }

    const float bt = bterm[col0 + m];
    float* op = out + (size_t)(row0 + quad * 4) * DOUT + col0 + m;
    #pragma unroll
    for (int r = 0; r < 4; ++r) op[(size_t)r * DOUT] = acc[r] + bt;
}

// ---------------- launcher ---------------------------------------------------
extern "C" void kernel_launch(void* const* d_in, const int* in_sizes, int n_in,
                              void* d_out, int out_size, void* d_ws, size_t ws_size,
                              hipStream_t stream) {
    const float* x    = (const float*)d_in[0];   // [4096,128]
    const float* W    = (const float*)d_in[1];   // [128,128,9]
    const float* bias = (const float*)d_in[2];   // [128,128]
    const float* C    = (const float*)d_in[3];   // [128,128]
    float* out = (float*)d_out;                  // [4096,128]

    char* ws = (char*)d_ws;
    __bf16* BT    = (__bf16*)ws;                              // 128*1152*2 = 294,912 B
    float*  bterm = (float*)(ws + (size_t)DOUT * KK * 2);     // 512 B

    void* args[] = { (void*)&x, (void*)&W, (void*)&bias, (void*)&C,
                     (void*)&BT, (void*)&bterm, (void*)&out };
    hipLaunchCooperativeKernel((const void*)kan_kernel,
                               dim3(NBLK), dim3(NTHR), args, 0, stream);
}

// Round 4
// 76.366 us; speedup vs baseline: 1.4665x; 1.4665x over previous
//
#include <hip/hip_runtime.h>
#include <math.h>
#include <stdint.h>

// KANLayer: out[b,o] = sum_i C[i,o]*(sum_k basis_k(x[b,i])*W[i,o,k] + bias[i,o])
// = GEMM: out = feats[4096 x 1152] * Weff[1152 x 128] + bterm[o]
// R4: SINGLE standard kernel (R3's coop launch cost +37us — reverted).
//     Block = 32 rows x 64 cols; folds its own B-slice (W*C) into LDS per
//     K-chunk, basis-expands A-chunk into LDS, MFMA accumulates across 4
//     chunks. No global BT, no second dispatch, no grid sync.

#define DIN   128
#define DOUT  128
#define NB    9
#define KK    (DIN * NB)        // 1152
#define BATCH 4096
#define BROWS 32                // batch rows per block
#define BCOLS 64                // out cols per block
#define CHUNK_I 32              // input dims per K-chunk
#define CHUNK_K (CHUNK_I * NB)  // 288
#define NCHUNK  (DIN / CHUNK_I) // 4
#define BSTR  (CHUNK_K + 8)     // 296 bf16 row stride (148 dw = 20 mod 32 -> 2-way, free)
#define NTHR  512

typedef __bf16 bf16x8 __attribute__((ext_vector_type(8)));
typedef float  f32x4  __attribute__((ext_vector_type(4)));

__global__ __launch_bounds__(NTHR, 1) void kan_kernel(const float* __restrict__ x,
                                                      const float* __restrict__ W,
                                                      const float* __restrict__ bias,
                                                      const float* __restrict__ C,
                                                      float* __restrict__ out) {
    __shared__ __bf16 Bs[BCOLS * BSTR];   // 37,888 B
    __shared__ __bf16 As[BROWS * BSTR];   // 18,944 B
    __shared__ float  btl[BCOLS];         //    256 B   (total 57,088 B)

    const int t    = threadIdx.x;
    const int rowg = blockIdx.x >> 1;           // 0..127
    const int colg = blockIdx.x & 1;            // 0..1
    const int row0 = rowg * BROWS;
    const int col0 = colg * BCOLS;

    // ---- bterm for this block's 64 cols (one wave, coalesced) ----
    if (t < BCOLS) {
        const int o = col0 + t;
        float s = 0.0f;
        #pragma unroll 8
        for (int i = 0; i < DIN; ++i)
            s += bias[i * DOUT + o] * C[i * DOUT + o];
        btl[t] = s;
    }

    const int lane = t & 63;
    const int wave = t >> 6;                    // 0..7
    const int m    = lane & 15;
    const int quad = lane >> 4;
    const int rt   = wave >> 2;                 // 0..1 row tile
    const int ct   = wave & 3;                  // 0..3 col tile

    f32x4 acc = {0.0f, 0.0f, 0.0f, 0.0f};

    for (int c = 0; c < NCHUNK; ++c) {
        if (c > 0) __syncthreads();             // prior chunk's LDS reads done

        // ---- fold W*C -> Bs[ol][i_l*9+k], bf16. 1024 (ol,i2) pairs, 2 passes.
        // lanes sweep ol -> W reads form contiguous 2304B regions per i.
        #pragma unroll
        for (int pass = 0; pass < 2; ++pass) {
            const int p   = t + pass * NTHR;    // 0..1023
            const int ol  = p & 63;
            const int i_l = (p >> 6) * 2;       // 0,2,..,30
            const int i   = c * CHUNK_I + i_l;
            const int o   = col0 + ol;
            const float c0 = C[i * DOUT + o];
            const float c1 = C[(i + 1) * DOUT + o];
            const float* w0 = W + ((size_t)i * DOUT + o) * NB;
            const float* w1 = W + ((size_t)(i + 1) * DOUT + o) * NB;
            __bf16 tmp[18];
            #pragma unroll
            for (int k = 0; k < NB; ++k) {
                tmp[k]      = (__bf16)(w0[k] * c0);
                tmp[NB + k] = (__bf16)(w1[k] * c1);
            }
            // contiguous 18 bf16 = 9 dwords, dword-aligned (i_l even)
            uint32_t* dst = (uint32_t*)&Bs[ol * BSTR + i_l * NB];
            const uint32_t* src = (const uint32_t*)tmp;
            #pragma unroll
            for (int j = 0; j < 9; ++j) dst[j] = src[j];
        }

        // ---- basis expansion -> As[r][i_l*9+k]. 1024 (r,i_l) elems, 2 passes.
        #pragma unroll
        for (int pass = 0; pass < 2; ++pass) {
            const int e   = t + pass * NTHR;    // 0..1023
            const int r   = e >> 5;             // 0..31
            const int i_l = e & 31;
            const float v  = x[(size_t)(row0 + r) * DIN + c * CHUNK_I + i_l];
            const float av = fabsf(v);
            float f[NB];
            f[0] = v;
            f[1] = v * v;
            f[2] = v * v * v;
            f[3] = __expf(v);
            f[4] = __logf(av + 1.0f);
            f[5] = __builtin_sqrtf(av);
            f[6] = tanhf(v);
            f[7] = __sinf(v);
            f[8] = av;
            __bf16* dst = &As[r * BSTR + i_l * NB];
            #pragma unroll
            for (int k = 0; k < NB; ++k) dst[k] = (__bf16)f[k];
        }
        __syncthreads();

        // ---- MFMA: 9 K-steps of 32 ----
        // A-frag A[m][quad*8+j], B-frag Bs-row=(tile col) [m][quad*8+j]
        const __bf16* Ap = &As[(rt * 16 + m) * BSTR + quad * 8];
        const __bf16* Bp = &Bs[(ct * 16 + m) * BSTR + quad * 8];
        #pragma unroll 3
        for (int kc = 0; kc < CHUNK_K / 32; ++kc) {   // 9
            bf16x8 a = *(const bf16x8*)(Ap + kc * 32);
            bf16x8 b = *(const bf16x8*)(Bp + kc * 32);
            acc = __builtin_amdgcn_mfma_f32_16x16x32_bf16(a, b, acc, 0, 0, 0);
        }
    }

    // ---- epilogue: C/D layout col=lane&15, row=quad*4+reg ----
    const float bt = btl[ct * 16 + m];
    float* op = out + (size_t)(row0 + rt * 16 + quad * 4) * DOUT + col0 + ct * 16 + m;
    #pragma unroll
    for (int r = 0; r < 4; ++r) op[(size_t)r * DOUT] = acc[r] + bt;
}

// ---------------- launcher ---------------------------------------------------
extern "C" void kernel_launch(void* const* d_in, const int* in_sizes, int n_in,
                              void* d_out, int out_size, void* d_ws, size_t ws_size,
                              hipStream_t stream) {
    const float* x    = (const float*)d_in[0];   // [4096,128]
    const float* W    = (const float*)d_in[1];   // [128,128,9]
    const float* bias = (const float*)d_in[2];   // [128,128]
    const float* C    = (const float*)d_in[3];   // [128,128]
    float* out = (float*)d_out;                  // [4096,128]

    kan_kernel<<<(BATCH / BROWS) * (DOUT / BCOLS), NTHR, 0, stream>>>(x, W, bias, C, out);
}